// Round 2
// baseline (61.039 us; speedup 1.0000x reference)
//
#include <hip/hip_runtime.h>

// Problem constants
#define BB 256
#define GG 16
#define LL 16
#define CC 8192
#define KK 8
// GAMMA_NEG=4, GAMMA_POS=1, CLIP=0.05, EPS=1e-8

typedef float f32x4 __attribute__((ext_vector_type(4)));

__device__ __forceinline__ float sigmoid_fast(float x) {
    float u = __expf(-x);                        // v_mul + v_exp_f32
    return __builtin_amdgcn_rcpf(1.0f + u);      // v_add + v_rcp_f32
}

// target==0 loss element, simplified:
//   t = max(sigmoid(x) - 0.05, 0)   [== 1 - xn]
//   f_neg = -log(1-t) * t^4         (1-t >= 0.05 so EPS clamp is dead code)
__device__ __forceinline__ float f_neg(float x) {
    float s  = sigmoid_fast(x);
    float t  = fmaxf(s - 0.05f, 0.0f);
    float l  = __logf(1.0f - t);
    float t2 = t * t;
    return -l * (t2 * t2);
}

// target==1 loss element: f_pos = -log(max(s,eps)) * (1-s)
__device__ __forceinline__ float f_pos(float x) {
    float s = sigmoid_fast(x);
    float l = __logf(fmaxf(s, 1e-8f));
    return -l * (1.0f - s);
}

// ---------------------------------------------------------------------------
// Kernel 1: per-(g,b) row sum of f_neg over C=8192. One block per row.
// Single coalesced nontemporal float4 streaming pass over 128 MiB.
// ---------------------------------------------------------------------------
__global__ __launch_bounds__(256) void negsum_kernel(
    const float* __restrict__ logits, float* __restrict__ negsum) {
    const int row = blockIdx.x;                          // row = g*B + b
    const f32x4* rp = reinterpret_cast<const f32x4*>(logits) + (size_t)row * (CC / 4);
    float acc = 0.0f;
#pragma unroll
    for (int i = 0; i < (CC / 4) / 256; ++i) {           // 8 iters
        f32x4 v = __builtin_nontemporal_load(rp + threadIdx.x + i * 256);
        acc += (f_neg(v.x) + f_neg(v.y)) + (f_neg(v.z) + f_neg(v.w));
    }
#pragma unroll
    for (int off = 32; off > 0; off >>= 1) acc += __shfl_down(acc, off, 64);
    __shared__ float sm[4];
    if ((threadIdx.x & 63) == 0) sm[threadIdx.x >> 6] = acc;
    __syncthreads();
    if (threadIdx.x == 0) negsum[row] = (sm[0] + sm[1]) + (sm[2] + sm[3]);
}

// ---------------------------------------------------------------------------
// Kernel 2 (fused tail): one block, 1024 threads, 4 (b,l) pairs per thread.
// per_node = negsum[p*B+b] + sum over distinct labeled classes of
// (f_pos - f_neg); masked by valid; block-reduce; write mean.
// ---------------------------------------------------------------------------
__global__ __launch_bounds__(1024) void tail_kernel(
    const float* __restrict__ logits, const int* __restrict__ param,
    const int* __restrict__ label, const int* __restrict__ num,
    const float* __restrict__ negsum, float* __restrict__ out) {
    float sum = 0.0f;
#pragma unroll
    for (int i = 0; i < (BB * LL) / 1024; ++i) {         // 4 iters
        const int t  = threadIdx.x + i * 1024;           // (b,l) flat, l fastest
        const int b  = t >> 4;                           // t / LL
        const int pv = param[t];
        const int nv = num[t];
        const int4* lp = reinterpret_cast<const int4*>(label + (size_t)t * KK);
        int4 l0 = lp[0], l1 = lp[1];
        int cs[KK] = {l0.x, l0.y, l0.z, l0.w, l1.x, l1.y, l1.z, l1.w};
        if (pv >= 0) {                                   // valid mask
            const int p = min(pv, GG - 1);
            const int n = min(nv, KK);
            const float* rowp = logits + ((size_t)p * BB + b) * (size_t)CC;
            float per = negsum[p * BB + b];
#pragma unroll
            for (int k = 0; k < KK; ++k) {
                if (k < n) {
                    bool dup = false;
#pragma unroll
                    for (int j = 0; j < k; ++j) dup = dup || (cs[j] == cs[k]);
                    if (!dup) {                          // min(label_bit,1) clamp
                        float x = rowp[cs[k]];
                        per += f_pos(x) - f_neg(x);
                    }
                }
            }
            sum += per;
        }
    }
    // block reduction: wave shfl, then cross-wave via LDS
#pragma unroll
    for (int off = 32; off > 0; off >>= 1) sum += __shfl_down(sum, off, 64);
    __shared__ float sm[16];
    if ((threadIdx.x & 63) == 0) sm[threadIdx.x >> 6] = sum;
    __syncthreads();
    if (threadIdx.x < 64) {
        float v = (threadIdx.x < 16) ? sm[threadIdx.x] : 0.0f;
#pragma unroll
        for (int off = 8; off > 0; off >>= 1) v += __shfl_down(v, off, 64);
        if (threadIdx.x == 0) out[0] = v * (1.0f / (float)BB);
    }
}

extern "C" void kernel_launch(void* const* d_in, const int* in_sizes, int n_in,
                              void* d_out, int out_size, void* d_ws, size_t ws_size,
                              hipStream_t stream) {
    const float* logits = (const float*)d_in[0];   // (G, B, C) f32
    const int*   param  = (const int*)d_in[1];     // (B, L)
    const int*   label  = (const int*)d_in[2];     // (B, L, K)
    const int*   num    = (const int*)d_in[3];     // (B, L)
    float* out = (float*)d_out;
    float* negsum = (float*)d_ws;                  // G*B = 4096 floats

    negsum_kernel<<<GG * BB, 256, 0, stream>>>(logits, negsum);
    tail_kernel<<<1, 1024, 0, stream>>>(logits, param, label, num, negsum, out);
}

// Round 3
// 32.352 us; speedup vs baseline: 1.8867x; 1.8867x over previous
//
#include <hip/hip_runtime.h>

// Problem constants
#define BB 256
#define GG 16
#define LL 16
#define CC 8192
#define KK 8
// GAMMA_NEG=4, GAMMA_POS=1, CLIP=0.05, EPS=1e-8

typedef float f32x4 __attribute__((ext_vector_type(4)));

__device__ __forceinline__ float sigmoid_fast(float x) {
    float u = __expf(-x);                        // v_exp_f32
    return __builtin_amdgcn_rcpf(1.0f + u);      // v_rcp_f32
}

// target==0: t = max(s-0.05,0);  f_neg = -log(1-t) * t^4   (1-t >= 0.05 > EPS)
__device__ __forceinline__ float f_neg(float x) {
    float s  = sigmoid_fast(x);
    float t  = fmaxf(s - 0.05f, 0.0f);
    float l  = __logf(1.0f - t);
    float t2 = t * t;
    return -l * (t2 * t2);
}

// target==1: f_pos = -log(max(s,eps)) * (1-s)
__device__ __forceinline__ float f_pos(float x) {
    float s = sigmoid_fast(x);
    float l = __logf(fmaxf(s, 1e-8f));
    return -l * (1.0f - s);
}

// ---------------------------------------------------------------------------
// One block per (g,b) row (4096 blocks). Each block:
//  - streams its C=8192 row, summing f_neg               (coalesced float4)
//  - counts cnt[g,b] = #{l : param[b,l]>=0 && clip==g}   (wave-0 lanes 0..15)
//  - computes the pos-correction for pair (b, l=g)       (wave-0 lanes 0..7,
//    one scattered gather each, issued BEFORE the stream so latency hides)
//  partial[row] = cnt * rowsum + corrsum
// ---------------------------------------------------------------------------
__global__ __launch_bounds__(256) void main_kernel(
    const float* __restrict__ logits, const int* __restrict__ param,
    const int* __restrict__ label, const int* __restrict__ num,
    float* __restrict__ partial) {
    const int row = blockIdx.x;                  // g*BB + b
    const int g   = row >> 8;
    const int b   = row & (BB - 1);
    const int tid = threadIdx.x;

    // ---- wave-0 side work: issue all small/scattered loads first ----
    int   match   = 0;
    int   corr_on = 0;
    float xg      = 0.0f;
    if (tid < 64) {
        if (tid < LL) {                          // cnt contribution
            int pv = param[b * LL + tid];
            match = (pv >= 0) && (min(pv, GG - 1) == g);
        }
        const int t  = b * LL + g;               // this block's (b,l) pair
        const int pv = param[t];                 // broadcast load
        const int n  = min(num[t], KK);
        int myc = 0;
        if (tid < KK) myc = label[t * KK + tid];
        bool dup = false;                        // min(label_bit,1) clamp
#pragma unroll
        for (int j = 0; j < KK - 1; ++j) {
            int cj = __shfl(myc, j, 64);
            dup = dup || ((j < tid) && (cj == myc));
        }
        corr_on = (pv >= 0) && (tid < n) && !dup;
        if (corr_on) {
            const int p = min(pv, GG - 1);
            xg = logits[((size_t)p * BB + b) * CC + myc];   // scattered gather
        }
    }

    // ---- main streaming pass over row (g,b): 32 KB coalesced ----
    const f32x4* rp = reinterpret_cast<const f32x4*>(logits) + (size_t)row * (CC / 4);
    float acc = 0.0f;
#pragma unroll
    for (int i = 0; i < (CC / 4) / 256; ++i) {   // 8 iters
        f32x4 v = rp[tid + i * 256];
        acc += (f_neg(v.x) + f_neg(v.y)) + (f_neg(v.z) + f_neg(v.w));
    }
#pragma unroll
    for (int off = 32; off > 0; off >>= 1) acc += __shfl_down(acc, off, 64);
    __shared__ float sm[4];
    if ((tid & 63) == 0) sm[tid >> 6] = acc;
    __syncthreads();

    if (tid < 64) {
        float corr = corr_on ? (f_pos(xg) - f_neg(xg)) : 0.0f;
        int   cnt  = match;
#pragma unroll
        for (int off = 32; off > 0; off >>= 1) {
            corr += __shfl_down(corr, off, 64);
            cnt  += __shfl_down(cnt, off, 64);
        }
        if (tid == 0) {
            float rowsum = (sm[0] + sm[1]) + (sm[2] + sm[3]);
            partial[row] = (float)cnt * rowsum + corr;
        }
    }
}

// ---------------------------------------------------------------------------
// Final: reduce 4096 partials -> mean over B.
// ---------------------------------------------------------------------------
__global__ __launch_bounds__(1024) void reduce_kernel(
    const float* __restrict__ partial, float* __restrict__ out) {
    const f32x4 v = reinterpret_cast<const f32x4*>(partial)[threadIdx.x];
    float s = (v.x + v.y) + (v.z + v.w);
#pragma unroll
    for (int off = 32; off > 0; off >>= 1) s += __shfl_down(s, off, 64);
    __shared__ float sm[16];
    if ((threadIdx.x & 63) == 0) sm[threadIdx.x >> 6] = s;
    __syncthreads();
    if (threadIdx.x < 64) {
        float v2 = (threadIdx.x < 16) ? sm[threadIdx.x] : 0.0f;
#pragma unroll
        for (int off = 8; off > 0; off >>= 1) v2 += __shfl_down(v2, off, 64);
        if (threadIdx.x == 0) out[0] = v2 * (1.0f / (float)BB);
    }
}

extern "C" void kernel_launch(void* const* d_in, const int* in_sizes, int n_in,
                              void* d_out, int out_size, void* d_ws, size_t ws_size,
                              hipStream_t stream) {
    const float* logits = (const float*)d_in[0];   // (G, B, C) f32
    const int*   param  = (const int*)d_in[1];     // (B, L)
    const int*   label  = (const int*)d_in[2];     // (B, L, K)
    const int*   num    = (const int*)d_in[3];     // (B, L)
    float* out = (float*)d_out;
    float* partial = (float*)d_ws;                 // G*B = 4096 floats

    main_kernel<<<GG * BB, 256, 0, stream>>>(logits, param, label, num, partial);
    reduce_kernel<<<1, 1024, 0, stream>>>(partial, out);
}